// Round 1
// 369.507 us; speedup vs baseline: 1.0015x; 1.0015x over previous
//
#include <hip/hip_runtime.h>
#include <hip/hip_bf16.h>

// messages[e,:] = edge_matrices[type(e)] @ h_w[e,:]
// Inputs (all FLOAT32 per reference): h_v (unused), h_w (E,128),
// edge_features (E,8) one-hot, edge_matrices (8,128,128). Output f32 (E,128).
//
// Grid (chunk=2560, type). Per block: ballot-compacted match list, then a
// single-__syncthreads-per-group double-buffered pipeline:
//   barrier -> issue next group's gather loads (regs) -> MFMA+store current
//   group from LDS -> pack/ds_write prefetched rows into other buffer.
// MFMA operands are SWAPPED vs the naive form (matrix = A operand, edges = B)
// so D rows = h -> each lane holds 4 contiguous h values -> float4 stores.

#define NEDGES 320000
#define HIDDEN 128
#define CHUNK  2560            // 320000 / 2560 = 125 chunks exactly
#define RSTRIDE 272            // Abuf row stride bytes (17*16B) -> conflict-light
#define HALF   (64 * RSTRIDE)  // 17408 B per buffer

typedef __bf16 bf16x8 __attribute__((ext_vector_type(8)));
typedef float  f32x4  __attribute__((ext_vector_type(4)));

__device__ inline bf16x8 pack8(const float4 v0, const float4 v1) {
    bf16x8 p;
    p[0] = (__bf16)v0.x; p[1] = (__bf16)v0.y; p[2] = (__bf16)v0.z; p[3] = (__bf16)v0.w;
    p[4] = (__bf16)v1.x; p[5] = (__bf16)v1.y; p[6] = (__bf16)v1.z; p[7] = (__bf16)v1.w;
    return p;
}

__global__ __launch_bounds__(256, 4) void matrix_message_kernel(
    const float* __restrict__ h_w,   // (E,128) f32
    const float* __restrict__ ef,    // (E,8)   f32 one-hot
    const float* __restrict__ M,     // (8,128,128) f32
    float*       __restrict__ out)   // (E,128) f32
{
    __shared__ unsigned short list[CHUNK];
    __shared__ int cnt;
    __shared__ __align__(16) unsigned char Abuf[2][HALF];

    const int tid  = threadIdx.x;
    const int w    = tid >> 6;       // wave 0..3 -> h-slice [32w, 32w+32)
    const int lane = tid & 63;
    const int q    = lane >> 4;      // quad 0..3
    const int c    = lane & 15;
    const int k    = blockIdx.y;     // edge type
    const int e0   = blockIdx.x * CHUNK;

    if (tid == 0) cnt = 0;

    // Matrix fragments for this wave's 32 h-columns. Used as the MFMA *A*
    // operand (m = h): A[m=c][kslice j] = M_k[h=32w+nt*16+c][d=kk*32+q*8+j].
    const float* Mb = M + (size_t)k * (HIDDEN * HIDDEN);
    bf16x8 b[2][4];
#pragma unroll
    for (int nt = 0; nt < 2; ++nt)
#pragma unroll
        for (int kk = 0; kk < 4; ++kk) {
            const int h = 32 * w + nt * 16 + c;
            const float4* s4 = (const float4*)(Mb + (size_t)h * HIDDEN + kk * 32 + q * 8);
            b[nt][kk] = pack8(s4[0], s4[1]);
        }

    __syncthreads();  // cnt = 0 visible

    // Ballot-compaction scan: one LDS atomic per wave per 256-edge strip.
#pragma unroll
    for (int t0 = 0; t0 < CHUNK; t0 += 256) {
        const int t = t0 + tid;
        const bool m = ef[(size_t)(e0 + t) * 8 + k] > 0.5f;
        const unsigned long long mask = __ballot(m);
        int base = 0;
        if (lane == 0) base = atomicAdd(&cnt, __popcll(mask));
        base = __shfl(base, 0);
        if (m) {
            const int off = __popcll(mask & ((1ull << lane) - 1ull));
            list[base + off] = (unsigned short)t;
        }
    }
    __syncthreads();

    const int n_g = cnt;
    if (n_g == 0) return;            // block-uniform; ~impossible but safe

    const int rr = tid >> 4;         // row-within-group this thread gathers
    const int cc = tid & 15;         // 32B d-segment within the row

    // Prologue: gather group 0 into regs, pack to bf16, stage into buf0.
    float4 p0[4], p1[4];
#pragma unroll
    for (int r4 = 0; r4 < 4; ++r4) {
        const int idx = r4 * 16 + rr;
        const int e_loc = list[(idx < n_g) ? idx : 0];
        const float4* src = (const float4*)(h_w + (size_t)(e0 + e_loc) * HIDDEN + cc * 8);
        p0[r4] = src[0];
        p1[r4] = src[1];
    }
#pragma unroll
    for (int r4 = 0; r4 < 4; ++r4)
        *(bf16x8*)(&Abuf[0][(r4 * 16 + rr) * RSTRIDE + cc * 16]) = pack8(p0[r4], p1[r4]);

    int cur = 0;
    for (int g = 0; g < n_g; g += 64) {
        __syncthreads();  // buf[cur] staged+visible; buf[cur^1] free

        // Issue next group's gather NOW (no barrier between issue and the
        // consuming ds_write below -> latency hides under MFMA+stores).
        const bool pf = (g + 64 < n_g);
        if (pf) {
#pragma unroll
            for (int r4 = 0; r4 < 4; ++r4) {
                const int idx = g + 64 + r4 * 16 + rr;
                const int e_loc = list[(idx < n_g) ? idx : 0];
                const float4* src = (const float4*)(h_w + (size_t)(e0 + e_loc) * HIDDEN + cc * 8);
                p0[r4] = src[0];
                p1[r4] = src[1];
            }
        }

        // Compute current group's 4 edge-subtiles from buf[cur].
        const unsigned char* Ab = Abuf[cur];
        for (int s = 0; s < 4 && g + s * 16 < n_g; ++s) {
            bf16x8 a[4];  // B operand: B[kslice j][n=c] = h_w[list[g+s*16+c]][d]
#pragma unroll
            for (int kk = 0; kk < 4; ++kk)
                a[kk] = *(const bf16x8*)(Ab + (s * 16 + c) * RSTRIDE + kk * 64 + q * 16);

            f32x4 acc0 = {0.f, 0.f, 0.f, 0.f};
            f32x4 acc1 = {0.f, 0.f, 0.f, 0.f};
#pragma unroll
            for (int kk = 0; kk < 4; ++kk) {
                acc0 = __builtin_amdgcn_mfma_f32_16x16x32_bf16(b[0][kk], a[kk], acc0, 0, 0, 0);
                acc1 = __builtin_amdgcn_mfma_f32_16x16x32_bf16(b[1][kk], a[kk], acc1, 0, 0, 0);
            }

            // D: col = c = edge within subtile, row = q*4+reg = h offset.
            // Lane holds 4 consecutive h values -> two float4 stores.
            const int idx = g + s * 16 + c;
            if (idx < n_g) {
                float* dst = out + (size_t)(e0 + list[idx]) * HIDDEN + 32 * w + q * 4;
                *(float4*)dst        = *(const float4*)&acc0;
                *(float4*)(dst + 16) = *(const float4*)&acc1;
            }
        }

        // Consume prefetched rows: pack + stage into the other buffer.
        if (pf) {
            unsigned char* An = Abuf[cur ^ 1];
#pragma unroll
            for (int r4 = 0; r4 < 4; ++r4)
                *(bf16x8*)(&An[(r4 * 16 + rr) * RSTRIDE + cc * 16]) = pack8(p0[r4], p1[r4]);
        }
        cur ^= 1;
    }
}

extern "C" void kernel_launch(void* const* d_in, const int* in_sizes, int n_in,
                              void* d_out, int out_size, void* d_ws, size_t ws_size,
                              hipStream_t stream) {
    // d_in order: h_v (unused), h_w, edge_features, edge_matrices — all f32
    const float* h_w = (const float*)d_in[1];
    const float* ef  = (const float*)d_in[2];
    const float* M   = (const float*)d_in[3];
    float*       out = (float*)d_out;

    dim3 grid(NEDGES / CHUNK, 8, 1);   // 125 chunks x 8 types
    dim3 block(256, 1, 1);
    matrix_message_kernel<<<grid, block, 0, stream>>>(h_w, ef, M, out);
}